// Round 17
// baseline (40.323 us; speedup 1.0000x reference)
//
#include <hip/hip_runtime.h>
#include <math.h>

constexpr int BB   = 2;
constexpr int CC   = 64;
constexpr int HH   = 128;
constexpr int WW   = 128;
constexpr int OO   = 64;
constexpr int HWSZ = HH * WW;    // 16384
constexpr int HOWO = 16384;
constexpr int OMC  = 27;

typedef __attribute__((ext_vector_type(8))) short short8v;  // 8 bf16
typedef __attribute__((ext_vector_type(4))) float f32x4;
typedef unsigned short ushortT;

__device__ __forceinline__ ushortT f2bf(float x) {
    unsigned int u = __builtin_bit_cast(unsigned int, x);
    u = (u + 0x7FFFu + ((u >> 16) & 1u)) >> 16;   // RTNE
    return (ushortT)u;
}
__device__ __forceinline__ float bf2f(ushortT u) {
    return __builtin_bit_cast(float, (unsigned int)u << 16);
}

// ---------------------------------------------------------------------------
// xtpose_prep (round-15 verbatim): channels-last bf16 transposes + the
// wave-fragment-swizzled weights Wdswz [4][18][64][8], Womswz [2][18][64][8].
// ---------------------------------------------------------------------------
__global__ __launch_bounds__(256) void xtpose_prep(
    const float* __restrict__ xr, const float* __restrict__ xo,
    ushortT* __restrict__ xtr, ushortT* __restrict__ xto,
    const float* __restrict__ w_dcn, const float* __restrict__ w_om,
    ushortT* __restrict__ Wdswz, ushortT* __restrict__ Womswz)
{
    __shared__ float t[64][129];
    const int tid = threadIdx.x;
    const int bid = blockIdx.x;

    if (bid < 512) {
        const int by = bid & 255;            // b*128 + y
        const int b  = by >> 7, y = by & 127;
        const float* src = (bid < 256) ? xr : xo;
        ushortT*    dst  = (bid < 256) ? xtr : xto;

#pragma unroll
        for (int cc = 0; cc < 64; cc += 2) {
            const int c  = cc + (tid >> 7);
            const int xw = tid & 127;
            t[c][xw] = src[((size_t)(b * 64 + c) * 128 + y) * 128 + xw];
        }
        __syncthreads();

#pragma unroll
        for (int r = 0; r < 8; ++r) {
            const int idx = r * 256 + tid;
            const int xw  = idx >> 4;
            const int cq  = (idx & 15) << 2;
            ushort4 pk = make_ushort4(f2bf(t[cq][xw]), f2bf(t[cq + 1][xw]),
                                      f2bf(t[cq + 2][xw]), f2bf(t[cq + 3][xw]));
            *(ushort4*)(dst + (((size_t)by * 128 + xw) << 6) + cq) = pk;
        }
    } else {
        const int idx = (bid - 512) * 256 + tid;
        if (idx < 64 * 576) {                 // Wdswz
            const int j    = idx & 7;
            const int lane = (idx >> 3) & 63;
            const int ks   = (idx >> 9) % 18;
            const int wid  = idx / (8 * 64 * 18);
            const int l15  = lane & 15;
            const int l4   = lane >> 4;
            const int oc   = (wid << 4) + l15;
            const int k    = ks * 32 + l4 * 8 + j;
            const int kk   = k >> 6;
            const int c    = k & 63;
            Wdswz[idx] = f2bf(w_dcn[(oc * CC + c) * 9 + kk]);
        }
        if (idx < 32 * 576) {                 // Womswz
            const int j    = idx & 7;
            const int lane = (idx >> 3) & 63;
            const int ks   = (idx >> 9) % 18;
            const int half = idx / (8 * 64 * 18);
            const int l15  = lane & 15;
            const int l4   = lane >> 4;
            const int oc   = (half << 4) + l15;
            const int k    = ks * 32 + l4 * 8 + j;
            const int kk   = k >> 6;
            const int c    = k & 63;
            Womswz[idx] = (oc < OMC) ? f2bf(w_om[(oc * CC + c) * 9 + kk])
                                     : (ushortT)0;
        }
    }
}

__device__ __forceinline__ void bilinear_params(
    float oy, float ox, float m, int ho, int wo, int ky, int kx,
    float& w00, float& w01, float& w10, float& w11,
    int& i00, int& i01, int& i10, int& i11)
{
    const float yf = (float)(ho + ky - 1) + oy;
    const float xf = (float)(wo + kx - 1) + ox;
    const float y0 = floorf(yf), x0 = floorf(xf);
    const float ly = yf - y0, lx = xf - x0;
    const float hy = 1.f - ly, hx = 1.f - lx;
    const int iy0 = (int)y0, ix0 = (int)x0;
    const int iy1 = iy0 + 1, ix1 = ix0 + 1;
    const bool vy0 = (unsigned)iy0 < (unsigned)HH;
    const bool vy1 = (unsigned)iy1 < (unsigned)HH;
    const bool vx0 = (unsigned)ix0 < (unsigned)WW;
    const bool vx1 = (unsigned)ix1 < (unsigned)WW;
    w00 = (vy0 && vx0) ? hy * hx * m : 0.f;
    w01 = (vy0 && vx1) ? hy * lx * m : 0.f;
    w10 = (vy1 && vx0) ? ly * hx * m : 0.f;
    w11 = (vy1 && vx1) ? ly * lx * m : 0.f;
    const int cy0 = min(max(iy0, 0), HH - 1), cy1 = min(max(iy1, 0), HH - 1);
    const int cx0 = min(max(ix0, 0), WW - 1), cx1 = min(max(ix1, 0), WW - 1);
    i00 = cy0 * WW + cx0; i01 = cy0 * WW + cx1;
    i10 = cy1 * WW + cx0; i11 = cy1 * WW + cx1;
}

// ---------------------------------------------------------------------------
// gather helpers, 32-pixel blocks: 9 rounds of 32 tasks (task = rnd*32+tid/8,
// gpix = task&31, kk = task>>5); 3 rounds per superround, A/B pipelined.
// ---------------------------------------------------------------------------
__device__ __forceinline__ void gather_issue32(
    const int s, const int tid, const int pl, const size_t bbase,
    const float (*offm)[28], const ushortT* __restrict__ xtr,
    short8v (&pay)[3][4], float (&gw)[3][4], int (&wadr)[3])
{
    const int ch0 = (tid & 7) << 3;
#pragma unroll
    for (int rr = 0; rr < 3; ++rr) {
        const int rnd  = s * 3 + rr;
        const int task = rnd * 32 + (tid >> 3);
        const int gpix = task & 31;
        const int kk   = task >> 5;          // 0..8
        const int pg   = pl + gpix;
        const int gho  = pg >> 7, gwo = pg & 127;
        const int ky   = kk / 3, kx = kk - 3 * ky;

        float w00, w01, w10, w11; int i00, i01, i10, i11;
        bilinear_params(offm[gpix][2 * kk], offm[gpix][2 * kk + 1],
                        offm[gpix][18 + kk], gho, gwo, ky, kx,
                        w00, w01, w10, w11, i00, i01, i10, i11);
        gw[rr][0] = w00; gw[rr][1] = w01; gw[rr][2] = w10; gw[rr][3] = w11;

        pay[rr][0] = *(const short8v*)(xtr + ((bbase + i00) << 6) + ch0);
        pay[rr][1] = *(const short8v*)(xtr + ((bbase + i01) << 6) + ch0);
        pay[rr][2] = *(const short8v*)(xtr + ((bbase + i10) << 6) + ch0);
        pay[rr][3] = *(const short8v*)(xtr + ((bbase + i11) << 6) + ch0);

        // byte(k,pix) = pix*1152 + ((2k) ^ ((pix&7)<<4)), k = kk*64+ch0
        wadr[rr] = gpix * 1152 + ((((kk << 6) + ch0) << 1) ^ ((gpix & 7) << 4));
    }
}

__device__ __forceinline__ void gather_combine32(
    ushortT* vlds, const short8v (&pay)[3][4], const float (&gw)[3][4],
    const int (&wadr)[3])
{
#pragma unroll
    for (int rr = 0; rr < 3; ++rr) {
        short8v pk;
#pragma unroll
        for (int j = 0; j < 8; ++j) {
            const float v = gw[rr][0] * bf2f((ushortT)pay[rr][0][j]) +
                            gw[rr][1] * bf2f((ushortT)pay[rr][1][j]) +
                            gw[rr][2] * bf2f((ushortT)pay[rr][2][j]) +
                            gw[rr][3] * bf2f((ushortT)pay[rr][3][j]);
            pk[j] = (short)f2bf(v);
        }
        *(short8v*)((char*)vlds + wadr[rr]) = pk;
    }
}

// ---------------------------------------------------------------------------
// fused32: round-15 kernel at 32-pixel blocks, grid 1024 (4 blocks/CU,
// LDS 40.4 KB). Retry of r12 geometry with the weight-confound removed:
//   Phase 0: q/h-split conv (r12-verified mapping) + hoisted loads +
//            coalesced Womswz.
//   Phase 1: A/B pipelined gather, 3 superrounds.
//   Phase 2: 2-fragment GEMM (r12-verified) + coalesced Wdswz.
// ---------------------------------------------------------------------------
__global__ __launch_bounds__(256, 3) void fused32(
    const ushortT* __restrict__ xtr,     // bf16 channels-last input_real
    const ushortT* __restrict__ xto,     // bf16 channels-last input_offset
    const ushortT* __restrict__ Womswz,  // [2][18][64][8]
    const float* __restrict__ bom,       // [27]
    const ushortT* __restrict__ Wdswz,   // [4][18][64][8]
    const float* __restrict__ bd,        // [64]
    float* __restrict__ out,             // [B][64][HoWo]
    float* __restrict__ off_out)         // [B][18][HoWo]
{
    __shared__ ushortT vlds[32 * 576];   // 36 KB, row = pix (1152 B)
    __shared__ float offm[32][28];       // 3.5 KB

    const int tid  = threadIdx.x;
    const int lane = tid & 63;
    const int wid  = tid >> 6;           // 0..3
    const int l15  = lane & 15;
    const int l4   = lane >> 4;
    const int p0   = blockIdx.x * 32;
    const int b    = p0 >> 14;
    const int pl   = p0 & 16383;
    const size_t bbase = (size_t)(b << 14);

    // ---------------- Phase 0: offset/mask conv (q/h split + hoisted loads)
    {
        const int q = wid >> 1;              // oc group: 16q..16q+15
        const int h = wid & 1;               // pix group: 16h..16h+15
        const int lpix = (h << 4) + l15;
        const int pix  = pl + lpix;
        const int ho   = pix >> 7, wo = pix & 127;

        short8v xv[18];
        unsigned int vmask = 0;
#pragma unroll
        for (int ks = 0; ks < 18; ++ks) {
            const int kk = ks >> 1;
            const int ky = kk / 3, kx = kk - 3 * ky;
            const int iy = ho + ky - 1, ix = wo + kx - 1;
            if (((unsigned)iy < 128u) && ((unsigned)ix < 128u)) vmask |= (1u << ks);
            const int cy = min(max(iy, 0), 127), cx = min(max(ix, 0), 127);
            const int c0 = ((ks & 1) << 5) + (l4 << 3);
            xv[ks] = *(const short8v*)(xto + ((bbase + cy * 128 + cx) << 6) + c0);
        }

        f32x4 acc = {0.f, 0.f, 0.f, 0.f};
        const short8v zero8 = {0, 0, 0, 0, 0, 0, 0, 0};
        const ushortT* womL = Womswz + ((q * 18) << 9) + (lane << 3);

#pragma unroll
        for (int ks = 0; ks < 18; ++ks) {
            const short8v bf = (vmask & (1u << ks)) ? xv[ks] : zero8;
            const short8v ah = *(const short8v*)(womL + (ks << 9));
            acc = __builtin_amdgcn_mfma_f32_16x16x32_bf16(ah, bf, acc, 0, 0, 0);
        }

        // C/D: col = l15 (pix), row = l4*4 + r (oc within group)
#pragma unroll
        for (int r = 0; r < 4; ++r) {
            const int oc = (q << 4) + (l4 << 2) + r;
            if (oc < 18) {
                const float v = acc[r] + bom[oc];
                offm[lpix][oc] = v;
                off_out[(b * 18 + oc) * HOWO + pix] = v;
            } else if (oc < OMC) {
                offm[lpix][oc] = 1.f / (1.f + expf(-(acc[r] + bom[oc])));
            }
        }
    }
    __syncthreads();

    // ---------------- Phase 1: pipelined gather (3 superrounds, A/B)
    {
        short8v payA[3][4], payB[3][4];
        float gwA[3][4], gwB[3][4];
        int wA[3], wB[3];

        gather_issue32(0, tid, pl, bbase, offm, xtr, payA, gwA, wA);
        gather_issue32(1, tid, pl, bbase, offm, xtr, payB, gwB, wB);
        gather_combine32(vlds, payA, gwA, wA);
        gather_issue32(2, tid, pl, bbase, offm, xtr, payA, gwA, wA);
        gather_combine32(vlds, payB, gwB, wB);
        gather_combine32(vlds, payA, gwA, wA);
    }
    __syncthreads();

    // ---------------- Phase 2: GEMM, 2 fragments, coalesced weights
    {
        const int oc0 = wid << 4;
        const ushortT* wdL = Wdswz + ((wid * 18) << 9) + (lane << 3);
        const int swz = (l15 & 7) << 4;
        const int kl  = l4 << 4;

        f32x4 ac0 = {0.f, 0.f, 0.f, 0.f};
        f32x4 ac1 = {0.f, 0.f, 0.f, 0.f};

#pragma unroll
        for (int ks = 0; ks < 18; ++ks) {
            const short8v ahi = *(const short8v*)(wdL + (ks << 9));
            const int inrow = ((ks << 6) + kl) ^ swz;
            const char* base = (const char*)vlds + inrow;
            const short8v b0 = *(const short8v*)(base + (l15 + 0)  * 1152);
            const short8v b1 = *(const short8v*)(base + (l15 + 16) * 1152);
            ac0 = __builtin_amdgcn_mfma_f32_16x16x32_bf16(ahi, b0, ac0, 0, 0, 0);
            ac1 = __builtin_amdgcn_mfma_f32_16x16x32_bf16(ahi, b1, ac1, 0, 0, 0);
        }

#pragma unroll
        for (int r = 0; r < 4; ++r) {
            const int oc = oc0 + (l4 << 2) + r;
            const float bias = bd[oc];
            const size_t ob = ((size_t)(b * OO + oc)) * HOWO + pl + l15;
            out[ob + 0]  = ac0[r] + bias;
            out[ob + 16] = ac1[r] + bias;
        }
    }
}

// ---------------------------------------------------------------------------
// Mid tier (round-4, proven)
// ---------------------------------------------------------------------------
__global__ __launch_bounds__(256) void prep_transpose(
    const float* __restrict__ w_dcn, const float* __restrict__ w_om,
    float* __restrict__ wt_dcn, float* __restrict__ wt_om)
{
    int idx = blockIdx.x * 256 + threadIdx.x;
    if (idx < 9 * 64 * 64) {
        int o  = idx & 63;
        int c  = (idx >> 6) & 63;
        int kk = idx >> 12;
        wt_dcn[idx] = w_dcn[(o * CC + c) * 9 + kk];
    }
    if (idx < 9 * 64 * 28) {
        int o    = idx % 28;
        int rest = idx / 28;
        int c    = rest & 63;
        int kk   = rest >> 6;
        wt_om[idx] = (o < OMC) ? w_om[(o * CC + c) * 9 + kk] : 0.f;
    }
}

__global__ __launch_bounds__(256) void conv_om2(
    const float* __restrict__ x, const float* __restrict__ wtom,
    const float* __restrict__ bom, float* __restrict__ off_out,
    float* __restrict__ mask_out)
{
    const int pg  = blockIdx.x * 256 + threadIdx.x;
    const int b   = pg >> 14;
    const int p   = pg & 16383;
    const int ho  = p >> 7, wo = p & 127;
    const int oc0 = blockIdx.y << 3;

    float acc[8];
#pragma unroll
    for (int j = 0; j < 8; ++j) acc[j] = 0.f;

    const float* xb = x + (size_t)b * CC * HWSZ;
    for (int c = 0; c < CC; ++c) {
        const float* xc = xb + c * HWSZ;
        float t[9];
#pragma unroll
        for (int kh = 0; kh < 3; ++kh) {
            const int ih = ho + kh - 1;
            const bool rv = (unsigned)ih < (unsigned)HH;
#pragma unroll
            for (int kw = 0; kw < 3; ++kw) {
                const int iw = wo + kw - 1;
                t[kh * 3 + kw] =
                    (rv && (unsigned)iw < (unsigned)WW) ? xc[ih * WW + iw] : 0.f;
            }
        }
#pragma unroll
        for (int kk = 0; kk < 9; ++kk) {
            const float tv = t[kk];
            const float4* wr = (const float4*)(wtom + ((kk << 6) + c) * 28 + oc0);
            const float4 w0 = wr[0];
            const float4 w1 = wr[1];
            acc[0] += tv * w0.x; acc[1] += tv * w0.y;
            acc[2] += tv * w0.z; acc[3] += tv * w0.w;
            acc[4] += tv * w1.x; acc[5] += tv * w1.y;
            acc[6] += tv * w1.z; acc[7] += tv * w1.w;
        }
    }
#pragma unroll
    for (int j = 0; j < 8; ++j) {
        const int oc = oc0 + j;
        if (oc < 18) {
            off_out[(b * 18 + oc) * HOWO + p] = acc[j] + bom[oc];
        } else if (oc < OMC) {
            mask_out[(b * 9 + (oc - 18)) * HOWO + p] =
                1.f / (1.f + expf(-(acc[j] + bom[oc])));
        }
    }
}

__global__ __launch_bounds__(256) void dcn2(
    const float* __restrict__ xr, const float* __restrict__ off,
    const float* __restrict__ mask, const float* __restrict__ wtd,
    const float* __restrict__ bd, float* __restrict__ out)
{
    __shared__ float offm[32][29];
    __shared__ float vtile[64 * 33];

    const int tid  = threadIdx.x;
    const int pixl = tid & 31;
    const int grp  = tid >> 5;
    const int p0g  = blockIdx.x * 32;
    const int b    = p0g >> 14;
    const int p0   = p0g & 16383;
    const int p    = p0 + pixl;
    const int ho   = p >> 7, wo = p & 127;

    for (int it = tid; it < 32 * 27; it += 256) {
        const int pp = it & 31;
        const int o  = it >> 5;
        offm[pp][o] = (o < 18)
            ? off[(b * 18 + o) * HOWO + p0 + pp]
            : mask[(b * 9 + (o - 18)) * HOWO + p0 + pp];
    }
    __syncthreads();

    float acc[8];
#pragma unroll
    for (int j = 0; j < 8; ++j) acc[j] = 0.f;

    const float* xrb = xr + (size_t)b * CC * HWSZ;

    for (int kk = 0; kk < 9; ++kk) {
        {
            const int ky = kk / 3, kx = kk - ky * 3;
            float w00, w01, w10, w11; int i00, i01, i10, i11;
            bilinear_params(offm[pixl][2 * kk], offm[pixl][2 * kk + 1],
                            offm[pixl][18 + kk], ho, wo, ky, kx,
                            w00, w01, w10, w11, i00, i01, i10, i11);
            const float* xg = xrb + (grp << 3) * HWSZ;
#pragma unroll
            for (int i = 0; i < 8; ++i) {
                const float* xc = xg + i * HWSZ;
                const float v = w00 * xc[i00] + w01 * xc[i01] +
                                w10 * xc[i10] + w11 * xc[i11];
                vtile[((grp << 3) + i) * 33 + pixl] = v;
            }
        }
        __syncthreads();

        const float* wk = wtd + (kk << 12) + (grp << 3);
#pragma unroll 8
        for (int c = 0; c < 64; ++c) {
            const float v = vtile[c * 33 + pixl];
            const float4* wr = (const float4*)(wk + (c << 6));
            const float4 w0 = wr[0];
            const float4 w1 = wr[1];
            acc[0] += v * w0.x; acc[1] += v * w0.y;
            acc[2] += v * w0.z; acc[3] += v * w0.w;
            acc[4] += v * w1.x; acc[5] += v * w1.y;
            acc[6] += v * w1.z; acc[7] += v * w1.w;
        }
        __syncthreads();
    }

#pragma unroll
    for (int q = 0; q < 8; ++q) {
        const int oc = (grp << 3) + q;
        out[((size_t)(b * OO + oc)) * HOWO + p0 + pixl] = acc[q] + bd[oc];
    }
}

// ---------------------------------------------------------------------------
// Slow fallback (round-0, verified)
// ---------------------------------------------------------------------------
__global__ __launch_bounds__(256) void conv_om_slow(
    const float* __restrict__ x, const float* __restrict__ w,
    const float* __restrict__ bias, float* __restrict__ off_out)
{
    const int xid = blockIdx.x;
    const int b   = xid >> 6;
    const int p   = ((xid & 63) << 8) + threadIdx.x;
    const int ho  = p >> 7, wo = p & 127;
    const int oc0 = blockIdx.y << 4;

    float acc[16];
#pragma unroll
    for (int j = 0; j < 16; ++j) {
        const int oc = oc0 + j;
        acc[j] = (oc < OMC) ? bias[oc] : 0.f;
    }
    const float* xb = x + (size_t)b * CC * HWSZ;
    for (int c = 0; c < CC; ++c) {
        const float* xc = xb + c * HWSZ;
        float t[9];
#pragma unroll
        for (int kh = 0; kh < 3; ++kh) {
            const int ih = ho + kh - 1;
            const bool rv = (unsigned)ih < (unsigned)HH;
#pragma unroll
            for (int kw = 0; kw < 3; ++kw) {
                const int iw = wo + kw - 1;
                t[kh * 3 + kw] =
                    (rv && (unsigned)iw < (unsigned)WW) ? xc[ih * WW + iw] : 0.f;
            }
        }
#pragma unroll
        for (int j = 0; j < 16; ++j) {
            const int oc = oc0 + j;
            if (oc < OMC) {
                const float* wj = w + (size_t)(oc * CC + c) * 9;
                float s = 0.f;
#pragma unroll
                for (int kk = 0; kk < 9; ++kk) s += t[kk] * wj[kk];
                acc[j] += s;
            }
        }
    }
#pragma unroll
    for (int j = 0; j < 16; ++j) {
        const int oc = oc0 + j;
        if (oc < 18) off_out[(b * 18 + oc) * HOWO + p] = acc[j];
    }
}

__global__ __launch_bounds__(256) void dcn_slow(
    const float* __restrict__ xr, const float* __restrict__ off,
    const float* __restrict__ wd, const float* __restrict__ bd,
    float* __restrict__ out, const float* __restrict__ xo,
    const float* __restrict__ wom, const float* __restrict__ bom)
{
    const int xid = blockIdx.x;
    const int b   = xid >> 6;
    const int p   = ((xid & 63) << 8) + threadIdx.x;
    const int ho  = p >> 7, wo = p & 127;
    const int o0  = blockIdx.y << 4;

    float acc[16];
#pragma unroll
    for (int j = 0; j < 16; ++j) acc[j] = bd[o0 + j];
    const float* xb = xr + (size_t)b * CC * HWSZ;

    for (int kk = 0; kk < 9; ++kk) {
        const float oy = off[(b * 18 + 2 * kk) * HOWO + p];
        const float ox = off[(b * 18 + 2 * kk + 1) * HOWO + p];
        float a = bom[18 + kk];
        const float* xob = xo + (size_t)b * CC * HWSZ;
        for (int c = 0; c < CC; ++c) {
            const float* xc2 = xob + c * HWSZ;
            const float* wj  = wom + (size_t)((18 + kk) * CC + c) * 9;
#pragma unroll
            for (int kh = 0; kh < 3; ++kh) {
                const int ih = ho + kh - 1;
                if ((unsigned)ih < (unsigned)HH) {
#pragma unroll
                    for (int kw = 0; kw < 3; ++kw) {
                        const int iw = wo + kw - 1;
                        if ((unsigned)iw < (unsigned)WW)
                            a += xc2[ih * WW + iw] * wj[kh * 3 + kw];
                    }
                }
            }
        }
        const float m = 1.f / (1.f + expf(-a));
        const int ky = kk / 3, kx = kk - ky * 3;
        float w00, w01, w10, w11; int i00, i01, i10, i11;
        bilinear_params(oy, ox, m, ho, wo, ky, kx,
                        w00, w01, w10, w11, i00, i01, i10, i11);
#pragma unroll 4
        for (int c = 0; c < CC; ++c) {
            const float* xc = xb + c * HWSZ;
            const float v = w00 * xc[i00] + w01 * xc[i01] +
                            w10 * xc[i10] + w11 * xc[i11];
#pragma unroll
            for (int j = 0; j < 16; ++j)
                acc[j] += v * wd[(size_t)((o0 + j) * CC + c) * 9 + kk];
        }
    }
#pragma unroll
    for (int j = 0; j < 16; ++j)
        out[((size_t)b * OO + o0 + j) * HOWO + p] = acc[j];
}

// ---------------------------------------------------------------------------
extern "C" void kernel_launch(void* const* d_in, const int* in_sizes, int n_in,
                              void* d_out, int out_size, void* d_ws, size_t ws_size,
                              hipStream_t stream)
{
    const float* x_off  = (const float*)d_in[0];
    const float* x_real = (const float*)d_in[1];
    const float* w_om   = (const float*)d_in[2];
    const float* b_om   = (const float*)d_in[3];
    const float* w_dcn  = (const float*)d_in[4];
    const float* b_dcn  = (const float*)d_in[5];

    float* out = (float*)d_out;
    const int outElems = BB * OO * HOWO;
    float* off_out = out + outElems;                  // [B][18][HoWo]

    const size_t xtB   = (size_t)BB * HWSZ * CC * 2;    // 4,194,304 each
    const size_t wdB   = (size_t)64 * 576 * 2;          // 73,728
    const size_t womB  = (size_t)32 * 576 * 2;          // 36,864
    const size_t need_full = 2 * xtB + wdB + womB;      // 8,499,200

    const size_t wtDcnF = 9 * 64 * 64;
    const size_t wtOmF  = 9 * 64 * 28;
    const size_t need_mid = (wtDcnF + wtOmF + (size_t)BB * 9 * HOWO) * 4;

    if (ws_size >= need_full) {
        char* w = (char*)d_ws;
        ushortT* xtr    = (ushortT*)w;   w += xtB;
        ushortT* xto    = (ushortT*)w;   w += xtB;
        ushortT* Wdswz  = (ushortT*)w;   w += wdB;
        ushortT* Womswz = (ushortT*)w;

        hipLaunchKernelGGL(xtpose_prep, dim3(656), dim3(256), 0, stream,
                           x_real, x_off, xtr, xto, w_dcn, w_om,
                           Wdswz, Womswz);
        hipLaunchKernelGGL(fused32, dim3(1024), dim3(256), 0, stream,
                           xtr, xto, Womswz, b_om, Wdswz, b_dcn,
                           out, off_out);
    } else if (ws_size >= need_mid) {
        float* wtDcn   = (float*)d_ws;
        float* wtOm    = wtDcn + wtDcnF;
        float* maskBuf = wtOm + wtOmF;
        hipLaunchKernelGGL(prep_transpose, dim3(144), dim3(256), 0, stream,
                           w_dcn, w_om, wtDcn, wtOm);
        hipLaunchKernelGGL(conv_om2, dim3(128, 4), dim3(256), 0, stream,
                           x_off, wtOm, b_om, off_out, maskBuf);
        hipLaunchKernelGGL(dcn2, dim3(1024), dim3(256), 0, stream,
                           x_real, off_out, maskBuf, wtDcn, b_dcn, out);
    } else {
        hipLaunchKernelGGL(conv_om_slow, dim3(128, 2), dim3(256), 0, stream,
                           x_off, w_om, b_om, off_out);
        hipLaunchKernelGGL(dcn_slow, dim3(128, 4), dim3(256), 0, stream,
                           x_real, off_out, w_dcn, b_dcn, out,
                           x_off, w_om, b_om);
    }
}

// Round 18
// 34.196 us; speedup vs baseline: 1.1792x; 1.1792x over previous
//
#include <hip/hip_runtime.h>
#include <math.h>

constexpr int BB   = 2;
constexpr int CC   = 64;
constexpr int HH   = 128;
constexpr int WW   = 128;
constexpr int OO   = 64;
constexpr int HWSZ = HH * WW;    // 16384
constexpr int HOWO = 16384;
constexpr int OMC  = 27;

typedef __attribute__((ext_vector_type(8))) short short8v;  // 8 bf16
typedef __attribute__((ext_vector_type(4))) float f32x4;
typedef unsigned short ushortT;

__device__ __forceinline__ ushortT f2bf(float x) {
    unsigned int u = __builtin_bit_cast(unsigned int, x);
    u = (u + 0x7FFFu + ((u >> 16) & 1u)) >> 16;   // RTNE
    return (ushortT)u;
}
__device__ __forceinline__ float bf2f(ushortT u) {
    return __builtin_bit_cast(float, (unsigned int)u << 16);
}

// ---------------------------------------------------------------------------
// xtpose_prep: blocks 0..511 transpose NCHW fp32 -> channels-last bf16
// (0..255: input_real -> xtr, 256..511: input_offset -> xto);
// blocks 512..655 build WAVE-FRAGMENT-SWIZZLED bf16 weights:
//   Wdswz : element ((wid*18+ks)*64+lane)*8 + j  (oc = wid*16 + (lane&15);
//           k = ks*32 + (lane>>4)*8 + j)
//   Womswz: element ((half*18+ks)*64+lane)*8 + j (ocs >= 27 zero-padded)
// -> every weight load in the MFMA phases is wave-uniform base + lane*16B.
// ---------------------------------------------------------------------------
__global__ __launch_bounds__(256) void xtpose_prep(
    const float* __restrict__ xr, const float* __restrict__ xo,
    ushortT* __restrict__ xtr, ushortT* __restrict__ xto,
    const float* __restrict__ w_dcn, const float* __restrict__ w_om,
    ushortT* __restrict__ Wdswz, ushortT* __restrict__ Womswz)
{
    __shared__ float t[64][129];
    const int tid = threadIdx.x;
    const int bid = blockIdx.x;

    if (bid < 512) {
        const int by = bid & 255;            // b*128 + y
        const int b  = by >> 7, y = by & 127;
        const float* src = (bid < 256) ? xr : xo;
        ushortT*    dst  = (bid < 256) ? xtr : xto;

#pragma unroll
        for (int cc = 0; cc < 64; cc += 2) {
            const int c  = cc + (tid >> 7);
            const int xw = tid & 127;
            t[c][xw] = src[((size_t)(b * 64 + c) * 128 + y) * 128 + xw];
        }
        __syncthreads();

#pragma unroll
        for (int r = 0; r < 8; ++r) {
            const int idx = r * 256 + tid;
            const int xw  = idx >> 4;
            const int cq  = (idx & 15) << 2;
            ushort4 pk = make_ushort4(f2bf(t[cq][xw]), f2bf(t[cq + 1][xw]),
                                      f2bf(t[cq + 2][xw]), f2bf(t[cq + 3][xw]));
            *(ushort4*)(dst + (((size_t)by * 128 + xw) << 6) + cq) = pk;
        }
    } else {
        const int idx = (bid - 512) * 256 + tid;
        if (idx < 64 * 576) {                 // Wdswz: 4 groups x 18 ks x 64 lanes x 8
            const int j    = idx & 7;
            const int lane = (idx >> 3) & 63;
            const int ks   = (idx >> 9) % 18;
            const int wid  = idx / (8 * 64 * 18);
            const int l15  = lane & 15;
            const int l4   = lane >> 4;
            const int oc   = (wid << 4) + l15;
            const int k    = ks * 32 + l4 * 8 + j;
            const int kk   = k >> 6;
            const int c    = k & 63;
            Wdswz[idx] = f2bf(w_dcn[(oc * CC + c) * 9 + kk]);
        }
        if (idx < 32 * 576) {                 // Womswz: 2 halves x 18 ks x 64 x 8
            const int j    = idx & 7;
            const int lane = (idx >> 3) & 63;
            const int ks   = (idx >> 9) % 18;
            const int half = idx / (8 * 64 * 18);
            const int l15  = lane & 15;
            const int l4   = lane >> 4;
            const int oc   = (half << 4) + l15;
            const int k    = ks * 32 + l4 * 8 + j;
            const int kk   = k >> 6;
            const int c    = k & 63;
            Womswz[idx] = (oc < OMC) ? f2bf(w_om[(oc * CC + c) * 9 + kk])
                                     : (ushortT)0;
        }
    }
}

__device__ __forceinline__ void bilinear_params(
    float oy, float ox, float m, int ho, int wo, int ky, int kx,
    float& w00, float& w01, float& w10, float& w11,
    int& i00, int& i01, int& i10, int& i11)
{
    const float yf = (float)(ho + ky - 1) + oy;
    const float xf = (float)(wo + kx - 1) + ox;
    const float y0 = floorf(yf), x0 = floorf(xf);
    const float ly = yf - y0, lx = xf - x0;
    const float hy = 1.f - ly, hx = 1.f - lx;
    const int iy0 = (int)y0, ix0 = (int)x0;
    const int iy1 = iy0 + 1, ix1 = ix0 + 1;
    const bool vy0 = (unsigned)iy0 < (unsigned)HH;
    const bool vy1 = (unsigned)iy1 < (unsigned)HH;
    const bool vx0 = (unsigned)ix0 < (unsigned)WW;
    const bool vx1 = (unsigned)ix1 < (unsigned)WW;
    w00 = (vy0 && vx0) ? hy * hx * m : 0.f;
    w01 = (vy0 && vx1) ? hy * lx * m : 0.f;
    w10 = (vy1 && vx0) ? ly * hx * m : 0.f;
    w11 = (vy1 && vx1) ? ly * lx * m : 0.f;
    const int cy0 = min(max(iy0, 0), HH - 1), cy1 = min(max(iy1, 0), HH - 1);
    const int cx0 = min(max(ix0, 0), WW - 1), cx1 = min(max(ix1, 0), WW - 1);
    i00 = cy0 * WW + cx0; i01 = cy0 * WW + cx1;
    i10 = cy1 * WW + cx0; i11 = cy1 * WW + cx1;
}

// ---------------------------------------------------------------------------
// gather superround helpers (round-13 verbatim)
// ---------------------------------------------------------------------------
__device__ __forceinline__ void gather_issue(
    const int s, const int tid, const int pl, const size_t bbase,
    const float (*offm)[28], const ushortT* __restrict__ xtr,
    short8v (&pay)[3][4], float (&gw)[3][4], int (&wadr)[3])
{
    const int ch0 = (tid & 7) << 3;
#pragma unroll
    for (int rr = 0; rr < 3; ++rr) {
        const int rnd  = s * 3 + rr;
        const int task = rnd * 32 + (tid >> 3);
        const int gpix = task & 63;
        const int kk   = task >> 6;
        const int pg   = pl + gpix;
        const int gho  = pg >> 7, gwo = pg & 127;
        const int ky   = kk / 3, kx = kk - 3 * ky;

        float w00, w01, w10, w11; int i00, i01, i10, i11;
        bilinear_params(offm[gpix][2 * kk], offm[gpix][2 * kk + 1],
                        offm[gpix][18 + kk], gho, gwo, ky, kx,
                        w00, w01, w10, w11, i00, i01, i10, i11);
        gw[rr][0] = w00; gw[rr][1] = w01; gw[rr][2] = w10; gw[rr][3] = w11;

        pay[rr][0] = *(const short8v*)(xtr + ((bbase + i00) << 6) + ch0);
        pay[rr][1] = *(const short8v*)(xtr + ((bbase + i01) << 6) + ch0);
        pay[rr][2] = *(const short8v*)(xtr + ((bbase + i10) << 6) + ch0);
        pay[rr][3] = *(const short8v*)(xtr + ((bbase + i11) << 6) + ch0);

        // byte(k,pix) = pix*1152 + ((2k) ^ ((pix&7)<<4)), k = kk*64+ch0
        wadr[rr] = gpix * 1152 + ((((kk << 6) + ch0) << 1) ^ ((gpix & 7) << 4));
    }
}

__device__ __forceinline__ void gather_combine(
    ushortT* vlds, const short8v (&pay)[3][4], const float (&gw)[3][4],
    const int (&wadr)[3])
{
#pragma unroll
    for (int rr = 0; rr < 3; ++rr) {
        short8v pk;
#pragma unroll
        for (int j = 0; j < 8; ++j) {
            const float v = gw[rr][0] * bf2f((ushortT)pay[rr][0][j]) +
                            gw[rr][1] * bf2f((ushortT)pay[rr][1][j]) +
                            gw[rr][2] * bf2f((ushortT)pay[rr][2][j]) +
                            gw[rr][3] * bf2f((ushortT)pay[rr][3][j]);
            pk[j] = (short)f2bf(v);
        }
        *(short8v*)((char*)vlds + wadr[rr]) = pk;
    }
}

// ---------------------------------------------------------------------------
// fused_mlp (round-15/16 verified best: 34.3 us total): 64-pixel blocks,
// grid 512, 2 barriers; hoisted phase-0 loads; A/B pipelined gather;
// single-bf16 wave-fragment-coalesced weights.
// ---------------------------------------------------------------------------
__global__ __launch_bounds__(256, 2) void fused_mlp(
    const ushortT* __restrict__ xtr,     // bf16 channels-last input_real
    const ushortT* __restrict__ xto,     // bf16 channels-last input_offset
    const ushortT* __restrict__ Womswz,  // [2][18][64][8]
    const float* __restrict__ bom,       // [27]
    const ushortT* __restrict__ Wdswz,   // [4][18][64][8]
    const float* __restrict__ bd,        // [64]
    float* __restrict__ out,             // [B][64][HoWo]
    float* __restrict__ off_out)         // [B][18][HoWo]
{
    __shared__ ushortT vlds[64 * 576];   // 72 KB, row = pix (1152 B)
    __shared__ float offm[64][28];       // 7 KB

    const int tid  = threadIdx.x;
    const int lane = tid & 63;
    const int wid  = tid >> 6;           // 0..3
    const int l15  = lane & 15;
    const int l4   = lane >> 4;
    const int p0   = blockIdx.x * 64;
    const int b    = p0 >> 14;
    const int pl   = p0 & 16383;
    const size_t bbase = (size_t)(b << 14);

    // ---------------- Phase 0: offset/mask conv, loads hoisted
    {
        const int lpix = (wid << 4) + l15;
        const int pix  = pl + lpix;
        const int ho   = pix >> 7, wo = pix & 127;

        short8v xv[18];
        unsigned int vmask = 0;
#pragma unroll
        for (int ks = 0; ks < 18; ++ks) {
            const int kk = ks >> 1;
            const int ky = kk / 3, kx = kk - 3 * ky;
            const int iy = ho + ky - 1, ix = wo + kx - 1;
            if (((unsigned)iy < 128u) && ((unsigned)ix < 128u)) vmask |= (1u << ks);
            const int cy = min(max(iy, 0), 127), cx = min(max(ix, 0), 127);
            const int c0 = ((ks & 1) << 5) + (l4 << 3);
            xv[ks] = *(const short8v*)(xto + ((bbase + cy * 128 + cx) << 6) + c0);
        }

        f32x4 acc0 = {0.f, 0.f, 0.f, 0.f};
        f32x4 acc1 = {0.f, 0.f, 0.f, 0.f};
        const short8v zero8 = {0, 0, 0, 0, 0, 0, 0, 0};
        const ushortT* womL = Womswz + (lane << 3);   // + (half*18+ks)*512

#pragma unroll
        for (int ks = 0; ks < 18; ++ks) {
            const short8v bf = (vmask & (1u << ks)) ? xv[ks] : zero8;
            const short8v ah0 = *(const short8v*)(womL + (ks << 9));
            const short8v ah1 = *(const short8v*)(womL + ((18 + ks) << 9));
            acc0 = __builtin_amdgcn_mfma_f32_16x16x32_bf16(ah0, bf, acc0, 0, 0, 0);
            acc1 = __builtin_amdgcn_mfma_f32_16x16x32_bf16(ah1, bf, acc1, 0, 0, 0);
        }

        // C/D: col = l15 (pix), row = l4*4 + r (oc)
#pragma unroll
        for (int r = 0; r < 4; ++r) {
            const int oca = (l4 << 2) + r;            // 0..15: offset
            const float va = acc0[r] + bom[oca];
            offm[lpix][oca] = va;
            off_out[(b * 18 + oca) * HOWO + pix] = va;
            const int ocb = 16 + (l4 << 2) + r;       // 16..31
            if (ocb < 18) {
                const float vb = acc1[r] + bom[ocb];
                offm[lpix][ocb] = vb;
                off_out[(b * 18 + ocb) * HOWO + pix] = vb;
            } else if (ocb < OMC) {
                offm[lpix][ocb] = 1.f / (1.f + expf(-(acc1[r] + bom[ocb])));
            }
        }
    }
    __syncthreads();

    // ---------------- Phase 1: pipelined gather (A/B superrounds, peeled)
    {
        short8v payA[3][4], payB[3][4];
        float gwA[3][4], gwB[3][4];
        int wA[3], wB[3];

        gather_issue(0, tid, pl, bbase, offm, xtr, payA, gwA, wA);
        gather_issue(1, tid, pl, bbase, offm, xtr, payB, gwB, wB);
        gather_combine(vlds, payA, gwA, wA);
        gather_issue(2, tid, pl, bbase, offm, xtr, payA, gwA, wA);
        gather_combine(vlds, payB, gwB, wB);
        gather_issue(3, tid, pl, bbase, offm, xtr, payB, gwB, wB);
        gather_combine(vlds, payA, gwA, wA);
        gather_issue(4, tid, pl, bbase, offm, xtr, payA, gwA, wA);
        gather_combine(vlds, payB, gwB, wB);
        gather_issue(5, tid, pl, bbase, offm, xtr, payB, gwB, wB);
        gather_combine(vlds, payA, gwA, wA);
        gather_combine(vlds, payB, gwB, wB);
    }
    __syncthreads();

    // ---------------- Phase 2: GEMM, coalesced fragment weights
    {
        const int oc0 = wid << 4;
        const ushortT* wdL = Wdswz + ((wid * 18) << 9) + (lane << 3);
        const int swz = (l15 & 7) << 4;
        const int kl  = l4 << 4;

        f32x4 ac0 = {0.f, 0.f, 0.f, 0.f};
        f32x4 ac1 = {0.f, 0.f, 0.f, 0.f};
        f32x4 ac2 = {0.f, 0.f, 0.f, 0.f};
        f32x4 ac3 = {0.f, 0.f, 0.f, 0.f};

#pragma unroll
        for (int ks = 0; ks < 18; ++ks) {
            const short8v ahi = *(const short8v*)(wdL + (ks << 9));
            const int inrow = ((ks << 6) + kl) ^ swz;   // (ks*32)*2 bytes + kl
            const char* base = (const char*)vlds + inrow;
            const short8v b0 = *(const short8v*)(base + (l15 + 0)  * 1152);
            const short8v b1 = *(const short8v*)(base + (l15 + 16) * 1152);
            const short8v b2 = *(const short8v*)(base + (l15 + 32) * 1152);
            const short8v b3 = *(const short8v*)(base + (l15 + 48) * 1152);
            ac0 = __builtin_amdgcn_mfma_f32_16x16x32_bf16(ahi, b0, ac0, 0, 0, 0);
            ac1 = __builtin_amdgcn_mfma_f32_16x16x32_bf16(ahi, b1, ac1, 0, 0, 0);
            ac2 = __builtin_amdgcn_mfma_f32_16x16x32_bf16(ahi, b2, ac2, 0, 0, 0);
            ac3 = __builtin_amdgcn_mfma_f32_16x16x32_bf16(ahi, b3, ac3, 0, 0, 0);
        }

#pragma unroll
        for (int r = 0; r < 4; ++r) {
            const int oc = oc0 + (l4 << 2) + r;
            const float bias = bd[oc];
            const size_t ob = ((size_t)(b * OO + oc)) * HOWO + pl + l15;
            out[ob + 0]  = ac0[r] + bias;
            out[ob + 16] = ac1[r] + bias;
            out[ob + 32] = ac2[r] + bias;
            out[ob + 48] = ac3[r] + bias;
        }
    }
}

// ---------------------------------------------------------------------------
// Mid tier (round-4, proven)
// ---------------------------------------------------------------------------
__global__ __launch_bounds__(256) void prep_transpose(
    const float* __restrict__ w_dcn, const float* __restrict__ w_om,
    float* __restrict__ wt_dcn, float* __restrict__ wt_om)
{
    int idx = blockIdx.x * 256 + threadIdx.x;
    if (idx < 9 * 64 * 64) {
        int o  = idx & 63;
        int c  = (idx >> 6) & 63;
        int kk = idx >> 12;
        wt_dcn[idx] = w_dcn[(o * CC + c) * 9 + kk];
    }
    if (idx < 9 * 64 * 28) {
        int o    = idx % 28;
        int rest = idx / 28;
        int c    = rest & 63;
        int kk   = rest >> 6;
        wt_om[idx] = (o < OMC) ? w_om[(o * CC + c) * 9 + kk] : 0.f;
    }
}

__global__ __launch_bounds__(256) void conv_om2(
    const float* __restrict__ x, const float* __restrict__ wtom,
    const float* __restrict__ bom, float* __restrict__ off_out,
    float* __restrict__ mask_out)
{
    const int pg  = blockIdx.x * 256 + threadIdx.x;
    const int b   = pg >> 14;
    const int p   = pg & 16383;
    const int ho  = p >> 7, wo = p & 127;
    const int oc0 = blockIdx.y << 3;

    float acc[8];
#pragma unroll
    for (int j = 0; j < 8; ++j) acc[j] = 0.f;

    const float* xb = x + (size_t)b * CC * HWSZ;
    for (int c = 0; c < CC; ++c) {
        const float* xc = xb + c * HWSZ;
        float t[9];
#pragma unroll
        for (int kh = 0; kh < 3; ++kh) {
            const int ih = ho + kh - 1;
            const bool rv = (unsigned)ih < (unsigned)HH;
#pragma unroll
            for (int kw = 0; kw < 3; ++kw) {
                const int iw = wo + kw - 1;
                t[kh * 3 + kw] =
                    (rv && (unsigned)iw < (unsigned)WW) ? xc[ih * WW + iw] : 0.f;
            }
        }
#pragma unroll
        for (int kk = 0; kk < 9; ++kk) {
            const float tv = t[kk];
            const float4* wr = (const float4*)(wtom + ((kk << 6) + c) * 28 + oc0);
            const float4 w0 = wr[0];
            const float4 w1 = wr[1];
            acc[0] += tv * w0.x; acc[1] += tv * w0.y;
            acc[2] += tv * w0.z; acc[3] += tv * w0.w;
            acc[4] += tv * w1.x; acc[5] += tv * w1.y;
            acc[6] += tv * w1.z; acc[7] += tv * w1.w;
        }
    }
#pragma unroll
    for (int j = 0; j < 8; ++j) {
        const int oc = oc0 + j;
        if (oc < 18) {
            off_out[(b * 18 + oc) * HOWO + p] = acc[j] + bom[oc];
        } else if (oc < OMC) {
            mask_out[(b * 9 + (oc - 18)) * HOWO + p] =
                1.f / (1.f + expf(-(acc[j] + bom[oc])));
        }
    }
}

__global__ __launch_bounds__(256) void dcn2(
    const float* __restrict__ xr, const float* __restrict__ off,
    const float* __restrict__ mask, const float* __restrict__ wtd,
    const float* __restrict__ bd, float* __restrict__ out)
{
    __shared__ float offm[32][29];
    __shared__ float vtile[64 * 33];

    const int tid  = threadIdx.x;
    const int pixl = tid & 31;
    const int grp  = tid >> 5;
    const int p0g  = blockIdx.x * 32;
    const int b    = p0g >> 14;
    const int p0   = p0g & 16383;
    const int p    = p0 + pixl;
    const int ho   = p >> 7, wo = p & 127;

    for (int it = tid; it < 32 * 27; it += 256) {
        const int pp = it & 31;
        const int o  = it >> 5;
        offm[pp][o] = (o < 18)
            ? off[(b * 18 + o) * HOWO + p0 + pp]
            : mask[(b * 9 + (o - 18)) * HOWO + p0 + pp];
    }
    __syncthreads();

    float acc[8];
#pragma unroll
    for (int j = 0; j < 8; ++j) acc[j] = 0.f;

    const float* xrb = xr + (size_t)b * CC * HWSZ;

    for (int kk = 0; kk < 9; ++kk) {
        {
            const int ky = kk / 3, kx = kk - ky * 3;
            float w00, w01, w10, w11; int i00, i01, i10, i11;
            bilinear_params(offm[pixl][2 * kk], offm[pixl][2 * kk + 1],
                            offm[pixl][18 + kk], ho, wo, ky, kx,
                            w00, w01, w10, w11, i00, i01, i10, i11);
            const float* xg = xrb + (grp << 3) * HWSZ;
#pragma unroll
            for (int i = 0; i < 8; ++i) {
                const float* xc = xg + i * HWSZ;
                const float v = w00 * xc[i00] + w01 * xc[i01] +
                                w10 * xc[i10] + w11 * xc[i11];
                vtile[((grp << 3) + i) * 33 + pixl] = v;
            }
        }
        __syncthreads();

        const float* wk = wtd + (kk << 12) + (grp << 3);
#pragma unroll 8
        for (int c = 0; c < 64; ++c) {
            const float v = vtile[c * 33 + pixl];
            const float4* wr = (const float4*)(wk + (c << 6));
            const float4 w0 = wr[0];
            const float4 w1 = wr[1];
            acc[0] += v * w0.x; acc[1] += v * w0.y;
            acc[2] += v * w0.z; acc[3] += v * w0.w;
            acc[4] += v * w1.x; acc[5] += v * w1.y;
            acc[6] += v * w1.z; acc[7] += v * w1.w;
        }
        __syncthreads();
    }

#pragma unroll
    for (int q = 0; q < 8; ++q) {
        const int oc = (grp << 3) + q;
        out[((size_t)(b * OO + oc)) * HOWO + p0 + pixl] = acc[q] + bd[oc];
    }
}

// ---------------------------------------------------------------------------
// Slow fallback (round-0, verified)
// ---------------------------------------------------------------------------
__global__ __launch_bounds__(256) void conv_om_slow(
    const float* __restrict__ x, const float* __restrict__ w,
    const float* __restrict__ bias, float* __restrict__ off_out)
{
    const int xid = blockIdx.x;
    const int b   = xid >> 6;
    const int p   = ((xid & 63) << 8) + threadIdx.x;
    const int ho  = p >> 7, wo = p & 127;
    const int oc0 = blockIdx.y << 4;

    float acc[16];
#pragma unroll
    for (int j = 0; j < 16; ++j) {
        const int oc = oc0 + j;
        acc[j] = (oc < OMC) ? bias[oc] : 0.f;
    }
    const float* xb = x + (size_t)b * CC * HWSZ;
    for (int c = 0; c < CC; ++c) {
        const float* xc = xb + c * HWSZ;
        float t[9];
#pragma unroll
        for (int kh = 0; kh < 3; ++kh) {
            const int ih = ho + kh - 1;
            const bool rv = (unsigned)ih < (unsigned)HH;
#pragma unroll
            for (int kw = 0; kw < 3; ++kw) {
                const int iw = wo + kw - 1;
                t[kh * 3 + kw] =
                    (rv && (unsigned)iw < (unsigned)WW) ? xc[ih * WW + iw] : 0.f;
            }
        }
#pragma unroll
        for (int j = 0; j < 16; ++j) {
            const int oc = oc0 + j;
            if (oc < OMC) {
                const float* wj = w + (size_t)(oc * CC + c) * 9;
                float s = 0.f;
#pragma unroll
                for (int kk = 0; kk < 9; ++kk) s += t[kk] * wj[kk];
                acc[j] += s;
            }
        }
    }
#pragma unroll
    for (int j = 0; j < 16; ++j) {
        const int oc = oc0 + j;
        if (oc < 18) off_out[(b * 18 + oc) * HOWO + p] = acc[j];
    }
}

__global__ __launch_bounds__(256) void dcn_slow(
    const float* __restrict__ xr, const float* __restrict__ off,
    const float* __restrict__ wd, const float* __restrict__ bd,
    float* __restrict__ out, const float* __restrict__ xo,
    const float* __restrict__ wom, const float* __restrict__ bom)
{
    const int xid = blockIdx.x;
    const int b   = xid >> 6;
    const int p   = ((xid & 63) << 8) + threadIdx.x;
    const int ho  = p >> 7, wo = p & 127;
    const int o0  = blockIdx.y << 4;

    float acc[16];
#pragma unroll
    for (int j = 0; j < 16; ++j) acc[j] = bd[o0 + j];
    const float* xb = xr + (size_t)b * CC * HWSZ;

    for (int kk = 0; kk < 9; ++kk) {
        const float oy = off[(b * 18 + 2 * kk) * HOWO + p];
        const float ox = off[(b * 18 + 2 * kk + 1) * HOWO + p];
        float a = bom[18 + kk];
        const float* xob = xo + (size_t)b * CC * HWSZ;
        for (int c = 0; c < CC; ++c) {
            const float* xc2 = xob + c * HWSZ;
            const float* wj  = wom + (size_t)((18 + kk) * CC + c) * 9;
#pragma unroll
            for (int kh = 0; kh < 3; ++kh) {
                const int ih = ho + kh - 1;
                if ((unsigned)ih < (unsigned)HH) {
#pragma unroll
                    for (int kw = 0; kw < 3; ++kw) {
                        const int iw = wo + kw - 1;
                        if ((unsigned)iw < (unsigned)WW)
                            a += xc2[ih * WW + iw] * wj[kh * 3 + kw];
                    }
                }
            }
        }
        const float m = 1.f / (1.f + expf(-a));
        const int ky = kk / 3, kx = kk - ky * 3;
        float w00, w01, w10, w11; int i00, i01, i10, i11;
        bilinear_params(oy, ox, m, ho, wo, ky, kx,
                        w00, w01, w10, w11, i00, i01, i10, i11);
#pragma unroll 4
        for (int c = 0; c < CC; ++c) {
            const float* xc = xb + c * HWSZ;
            const float v = w00 * xc[i00] + w01 * xc[i01] +
                            w10 * xc[i10] + w11 * xc[i11];
#pragma unroll
            for (int j = 0; j < 16; ++j)
                acc[j] += v * wd[(size_t)((o0 + j) * CC + c) * 9 + kk];
        }
    }
#pragma unroll
    for (int j = 0; j < 16; ++j)
        out[((size_t)b * OO + o0 + j) * HOWO + p] = acc[j];
}

// ---------------------------------------------------------------------------
extern "C" void kernel_launch(void* const* d_in, const int* in_sizes, int n_in,
                              void* d_out, int out_size, void* d_ws, size_t ws_size,
                              hipStream_t stream)
{
    const float* x_off  = (const float*)d_in[0];
    const float* x_real = (const float*)d_in[1];
    const float* w_om   = (const float*)d_in[2];
    const float* b_om   = (const float*)d_in[3];
    const float* w_dcn  = (const float*)d_in[4];
    const float* b_dcn  = (const float*)d_in[5];

    float* out = (float*)d_out;
    const int outElems = BB * OO * HOWO;
    float* off_out = out + outElems;                  // [B][18][HoWo]

    // Full tier: xtr, xto (bf16 channels-last), Wdswz, Womswz (frag-swizzled)
    const size_t xtB   = (size_t)BB * HWSZ * CC * 2;    // 4,194,304 each
    const size_t wdB   = (size_t)64 * 576 * 2;          // 73,728
    const size_t womB  = (size_t)32 * 576 * 2;          // 36,864
    const size_t need_full = 2 * xtB + wdB + womB;      // 8,499,200

    const size_t wtDcnF = 9 * 64 * 64;
    const size_t wtOmF  = 9 * 64 * 28;
    const size_t need_mid = (wtDcnF + wtOmF + (size_t)BB * 9 * HOWO) * 4;

    if (ws_size >= need_full) {
        char* w = (char*)d_ws;
        ushortT* xtr    = (ushortT*)w;   w += xtB;
        ushortT* xto    = (ushortT*)w;   w += xtB;
        ushortT* Wdswz  = (ushortT*)w;   w += wdB;
        ushortT* Womswz = (ushortT*)w;

        hipLaunchKernelGGL(xtpose_prep, dim3(656), dim3(256), 0, stream,
                           x_real, x_off, xtr, xto, w_dcn, w_om,
                           Wdswz, Womswz);
        hipLaunchKernelGGL(fused_mlp, dim3(512), dim3(256), 0, stream,
                           xtr, xto, Womswz, b_om, Wdswz, b_dcn,
                           out, off_out);
    } else if (ws_size >= need_mid) {
        float* wtDcn   = (float*)d_ws;
        float* wtOm    = wtDcn + wtDcnF;
        float* maskBuf = wtOm + wtOmF;
        hipLaunchKernelGGL(prep_transpose, dim3(144), dim3(256), 0, stream,
                           w_dcn, w_om, wtDcn, wtOm);
        hipLaunchKernelGGL(conv_om2, dim3(128, 4), dim3(256), 0, stream,
                           x_off, wtOm, b_om, off_out, maskBuf);
        hipLaunchKernelGGL(dcn2, dim3(1024), dim3(256), 0, stream,
                           x_real, off_out, maskBuf, wtDcn, b_dcn, out);
    } else {
        hipLaunchKernelGGL(conv_om_slow, dim3(128, 2), dim3(256), 0, stream,
                           x_off, w_om, b_om, off_out);
        hipLaunchKernelGGL(dcn_slow, dim3(128, 4), dim3(256), 0, stream,
                           x_real, off_out, w_dcn, b_dcn, out,
                           x_off, w_om, b_om);
    }
}